// Round 3
// baseline (399.037 us; speedup 1.0000x reference)
//
#include <hip/hip_runtime.h>

typedef unsigned short u16;
typedef unsigned int u32;
typedef __attribute__((ext_vector_type(4))) float f32x4;
typedef __attribute__((ext_vector_type(8))) short bf16x8;

#define T_DIM 2048
#define E_DIM 1024
#define NBATCH 8
#define BK 32
#define BUFB 32768  // one K-step buffer: A 16KB + B 16KB

struct alignas(8)  U16x4 { u16 x, y, z, w; };
struct alignas(16) F32x4 { float x, y, z, w; };

__device__ __forceinline__ u16 f2bf(float f) {
  u32 u = __float_as_uint(f);
  u += 0x7FFFu + ((u >> 16) & 1u);
  return (u16)(u >> 16);
}

__device__ __forceinline__ void gld16(u16* lds, const u16* g) {
  __builtin_amdgcn_global_load_lds((const __attribute__((address_space(1))) void*)g,
                                   (__attribute__((address_space(3))) void*)lds, 16, 0, 0);
}

// LDS bank swizzle: byte bits[5:4] ^= bits[9:8] (involution, 16B-uniform).
// Rows are 64B (BK=32 bf16): spreads 16-lane row-column reads to 2-way.
__device__ __forceinline__ u32 swz32(u32 x) { return x ^ ((x >> 4) & 0x30u); }

// Bijective XCD-aware block remap (m204 form).
__device__ __forceinline__ int xcd_swz(int orig, int nwg) {
  int q = nwg >> 3, r = nwg & 7;
  int x = orig & 7, l = orig >> 3;
  return (x < r ? x * (q + 1) : r * (q + 1) + (x - r) * q) + l;
}

// ---------------------------------------------------------------------------
// 256x256 tile, C = A * B^T, 512 threads (8 waves = 2M x 4N), BK=32.
// 4 LDS buffers, 3-step prefetch, 2 phases/step, counted vmcnt(8) per step.
// Requires nK >= 3.
// ---------------------------------------------------------------------------
__device__ __forceinline__ void gemm256(const u16* __restrict__ A, const u16* __restrict__ B,
                                        int lda, int ldb, int nK, u16* ldsu,
                                        f32x4 acc[8][4])
{
  char* lds0 = (char*)ldsu;
  const int tid = threadIdx.x;
  const int lane = tid & 63, wave = tid >> 6;
  const int wr = wave >> 2, wc = wave & 3;

  // Staging: linear LDS dest, pre-swizzled global source (both-sides involution).
  const u32 lin0 = (u32)tid * 16u;        // [0, 8192)
  const u32 lin1 = lin0 + 8192u;          // [8192, 16384)
  const u32 s0 = swz32(lin0), s1 = swz32(lin1);
  const u16* A0 = A + (size_t)(s0 >> 6) * lda + ((s0 & 63u) >> 1);
  const u16* A1 = A + (size_t)(s1 >> 6) * lda + ((s1 & 63u) >> 1);
  const u16* B0 = B + (size_t)(s0 >> 6) * ldb + ((s0 & 63u) >> 1);
  const u16* B1 = B + (size_t)(s1 >> 6) * ldb + ((s1 & 63u) >> 1);

  auto stageA = [&](int s) {
    char* dst = lds0 + (s & 3) * BUFB;
    gld16((u16*)(dst + lin0), A0 + s * BK);
    gld16((u16*)(dst + lin1), A1 + s * BK);
  };
  auto stageB = [&](int s) {
    char* dst = lds0 + (s & 3) * BUFB + 16384;
    gld16((u16*)(dst + lin0), B0 + s * BK);
    gld16((u16*)(dst + lin1), B1 + s * BK);
  };

  // Swizzled read offsets (step-invariant).
  const u32 colb = (u32)(lane >> 4) * 16u;
  u32 aoff[8], boff[4];
#pragma unroll
  for (int m = 0; m < 8; ++m)
    aoff[m] = swz32((u32)(wr * 128 + m * 16 + (lane & 15)) * 64u + colb);
#pragma unroll
  for (int n = 0; n < 4; ++n)
    boff[n] = swz32((u32)(wc * 64 + n * 16 + (lane & 15)) * 64u + colb) + 16384u;

  // Prologue: steps 0,1,2 in flight (12 loads/wave); step 0 ready after vmcnt(8).
  stageA(0); stageB(0); stageA(1); stageB(1); stageA(2); stageB(2);
  asm volatile("s_waitcnt vmcnt(8)\n\ts_barrier" ::: "memory");

  bf16x8 a[4], b[4];

  // Phase A: read a(m 0-3) + b(n 0-3), stage next A-half, barrier, 16 MFMA, barrier.
  auto phaseA = [&](int s, bool st) {
    const char* buf = lds0 + (s & 3) * BUFB;
#pragma unroll
    for (int m = 0; m < 4; ++m) a[m] = *(const bf16x8*)(buf + aoff[m]);
#pragma unroll
    for (int n = 0; n < 4; ++n) b[n] = *(const bf16x8*)(buf + boff[n]);
    if (st) stageA(s + 3);
    asm volatile("s_barrier" ::: "memory");
    __builtin_amdgcn_s_setprio(1);
#pragma unroll
    for (int m = 0; m < 4; ++m)
#pragma unroll
      for (int n = 0; n < 4; ++n)
        acc[m][n] = __builtin_amdgcn_mfma_f32_16x16x32_bf16(a[m], b[n], acc[m][n], 0, 0, 0);
    __builtin_amdgcn_s_setprio(0);
    asm volatile("s_barrier" ::: "memory");
  };
  // Phase B reads: a(m 4-7) reusing b regs; stage next B-half.
  auto phaseBreads = [&](int s, bool st) {
    const char* buf = lds0 + (s & 3) * BUFB;
#pragma unroll
    for (int m = 0; m < 4; ++m) a[m] = *(const bf16x8*)(buf + aoff[4 + m]);
    if (st) stageB(s + 3);
  };
  auto phaseBmfma = [&]() {
    __builtin_amdgcn_s_setprio(1);
#pragma unroll
    for (int m = 0; m < 4; ++m)
#pragma unroll
      for (int n = 0; n < 4; ++n)
        acc[4 + m][n] = __builtin_amdgcn_mfma_f32_16x16x32_bf16(a[m], b[n], acc[4 + m][n], 0, 0, 0);
    __builtin_amdgcn_s_setprio(0);
    asm volatile("s_barrier" ::: "memory");
  };

  int s = 0;
  for (; s < nK - 3; ++s) {
    phaseA(s, true);
    phaseBreads(s, true);
    // step s+1 guaranteed landed (oldest 4 of <=12 outstanding retire)
    asm volatile("s_waitcnt vmcnt(8)\n\ts_barrier" ::: "memory");
    phaseBmfma();
  }
  phaseA(s, false);
  phaseBreads(s, false);
  asm volatile("s_waitcnt vmcnt(4)\n\ts_barrier" ::: "memory");
  phaseBmfma();
  ++s;
  phaseA(s, false);
  phaseBreads(s, false);
  asm volatile("s_waitcnt vmcnt(0)\n\ts_barrier" ::: "memory");
  phaseBmfma();
  ++s;
  phaseA(s, false);
  phaseBreads(s, false);
  asm volatile("s_barrier" ::: "memory");
  phaseBmfma();
}

// fp32 -> bf16 convert, 4 elems/thread
__global__ __launch_bounds__(256) void k_cvt(const float* __restrict__ in, u16* __restrict__ out, int n4)
{
  int i = blockIdx.x * 256 + threadIdx.x;
  if (i >= n4) return;
  F32x4 v = *(const F32x4*)&in[(size_t)i * 4];
  U16x4 o;
  o.x = f2bf(v.x); o.y = f2bf(v.y); o.z = f2bf(v.z); o.w = f2bf(v.w);
  *(U16x4*)&out[(size_t)i * 4] = o;
}

// QKV projection: [M=nbc*T, 3E] = Xb * Wb^T + bias. Q,K row-major bf16; V transposed.
__global__ __launch_bounds__(512, 2) void k_qkv(const u16* __restrict__ Xb, const u16* __restrict__ Wb,
                                                const float* __restrict__ bias,
                                                u16* __restrict__ Q, u16* __restrict__ Kmat,
                                                u16* __restrict__ Vt)
{
  __shared__ __align__(16) u16 lds[4 * BUFB / 2];
  const int wg = xcd_swz(blockIdx.x, gridDim.x);
  const int my = wg / 12, nx = wg % 12;
  const int m0 = my * 256, n0 = nx * 256;
  const int tid = threadIdx.x, lane = tid & 63, wave = tid >> 6;
  const int wr = wave >> 2, wc = wave & 3;
  f32x4 acc[8][4] = {};
  gemm256(Xb + (size_t)m0 * E_DIM, Wb + (size_t)n0 * E_DIM, E_DIM, E_DIM, E_DIM / BK, lds, acc);

  const int region = nx >> 2;  // 0=Q 1=K 2=V (uniform per block)
#pragma unroll
  for (int n = 0; n < 4; ++n) {
    const int ng = n0 + wc * 64 + n * 16 + (lane & 15);
    const float bn = bias[ng];
    const int nl = ng & (E_DIM - 1);
#pragma unroll
    for (int m = 0; m < 8; ++m) {
      const int mg0 = m0 + wr * 128 + m * 16 + ((lane >> 4) << 2);
      if (region < 2) {
        u16* dst = region ? Kmat : Q;
#pragma unroll
        for (int r = 0; r < 4; ++r)
          dst[(size_t)(mg0 + r) * E_DIM + nl] = f2bf(acc[m][n][r] + bn);
      } else {
        const int bl = mg0 >> 11;            // chunk-local batch
        const int t0 = mg0 & (T_DIM - 1);
        U16x4 pk;
        pk.x = f2bf(acc[m][n][0] + bn);
        pk.y = f2bf(acc[m][n][1] + bn);
        pk.z = f2bf(acc[m][n][2] + bn);
        pk.w = f2bf(acc[m][n][3] + bn);
        *(U16x4*)&Vt[((size_t)bl * E_DIM + nl) * T_DIM + t0] = pk;
      }
    }
  }
}

// Causal score tiles (256x256): S = Q*K^T * scale (fp32), masked = -1e30
__global__ __launch_bounds__(512, 2) void k_scores(const u16* __restrict__ Q, const u16* __restrict__ Kmat,
                                                   float* __restrict__ S)
{
  __shared__ __align__(16) u16 lds[4 * BUFB / 2];
  const int wg = xcd_swz(blockIdx.x, gridDim.x);
  const int b = wg / 36;
  const int ti = wg % 36;
  int iq = 0;
  while ((iq + 1) * (iq + 2) / 2 <= ti) ++iq;
  const int ik = ti - iq * (iq + 1) / 2;
  const int tid = threadIdx.x, lane = tid & 63, wave = tid >> 6;
  const int wr = wave >> 2, wc = wave & 3;
  f32x4 acc[8][4] = {};
  const u16* Qp = Q    + (size_t)b * T_DIM * E_DIM + (size_t)iq * 256 * E_DIM;
  const u16* Kp = Kmat + (size_t)b * T_DIM * E_DIM + (size_t)ik * 256 * E_DIM;
  gemm256(Qp, Kp, E_DIM, E_DIM, E_DIM / BK, lds, acc);

  float* Sb = S + (size_t)b * T_DIM * T_DIM;
  const float scale = 0.03125f;  // 1/sqrt(1024)
#pragma unroll
  for (int n = 0; n < 4; ++n) {
    const int kg = ik * 256 + wc * 64 + n * 16 + (lane & 15);
#pragma unroll
    for (int m = 0; m < 8; ++m) {
      const int qg0 = iq * 256 + wr * 128 + m * 16 + ((lane >> 4) << 2);
#pragma unroll
      for (int r = 0; r < 4; ++r) {
        const int qg = qg0 + r;
        Sb[(size_t)qg * T_DIM + kg] = (kg <= qg) ? acc[m][n][r] * scale : -1e30f;
      }
    }
  }
}

// Row softmax stats: one wave per row; 256-tile-granular causal prefix.
__global__ __launch_bounds__(256) void k_stats(const float* __restrict__ S, u16* __restrict__ P,
                                               float* __restrict__ invl)
{
  const int wave = threadIdx.x >> 6, lane = threadIdx.x & 63;
  const int rg = blockIdx.x * 4 + wave;           // chunk-local row
  const int bl = rg >> 11, q = rg & (T_DIM - 1);
  const float* row = S + (size_t)bl * T_DIM * T_DIM + (size_t)q * T_DIM;
  u16* prow       = P + (size_t)bl * T_DIM * T_DIM + (size_t)q * T_DIM;
  const int Cend = ((q >> 8) + 1) << 8;

  float m = -3.4e38f;
  for (int c = lane * 4; c < Cend; c += 256) {
    F32x4 v = *(const F32x4*)&row[c];
    m = fmaxf(m, fmaxf(fmaxf(v.x, v.y), fmaxf(v.z, v.w)));
  }
#pragma unroll
  for (int off = 32; off; off >>= 1) m = fmaxf(m, __shfl_xor(m, off, 64));

  float l = 0.f;
  for (int c = lane * 4; c < Cend; c += 256) {
    F32x4 v = *(const F32x4*)&row[c];
    float e0 = __expf(v.x - m), e1 = __expf(v.y - m), e2 = __expf(v.z - m), e3 = __expf(v.w - m);
    l += e0 + e1 + e2 + e3;
    U16x4 pk; pk.x = f2bf(e0); pk.y = f2bf(e1); pk.z = f2bf(e2); pk.w = f2bf(e3);
    *(U16x4*)&prow[c] = pk;
  }
#pragma unroll
  for (int off = 32; off; off >>= 1) l += __shfl_xor(l, off, 64);
  if (lane == 0) invl[rg] = 1.f / l;
}

// PV: Y[q,e] = (1/l_q) * sum_k P[q,k] * Vt[e,k] over causal k prefix. fp32 out.
__global__ __launch_bounds__(512, 2) void k_pv(const u16* __restrict__ P, const u16* __restrict__ Vt,
                                               const float* __restrict__ invl, float* __restrict__ out,
                                               int batch0)
{
  __shared__ __align__(16) u16 lds[4 * BUFB / 2];
  const int wg = xcd_swz(blockIdx.x, gridDim.x);
  const int bl = wg >> 5, rr = wg & 31;
  const int iq = rr >> 2, ie = rr & 3;
  const int tid = threadIdx.x, lane = tid & 63, wave = tid >> 6;
  const int wr = wave >> 2, wc = wave & 3;
  f32x4 acc[8][4] = {};
  const u16* Ap = P  + (size_t)bl * T_DIM * T_DIM + (size_t)iq * 256 * T_DIM;
  const u16* Bp = Vt + (size_t)bl * E_DIM * T_DIM + (size_t)ie * 256 * T_DIM;
  gemm256(Ap, Bp, T_DIM, T_DIM, (iq + 1) * 8, lds, acc);

#pragma unroll
  for (int m = 0; m < 8; ++m) {
    const int qg0 = iq * 256 + wr * 128 + m * 16 + ((lane >> 4) << 2);
#pragma unroll
    for (int r = 0; r < 4; ++r) {
      const int qg = qg0 + r;
      const float il = invl[bl * T_DIM + qg];
      float* orow = out + ((size_t)(batch0 + bl) * T_DIM + qg) * E_DIM;
#pragma unroll
      for (int n = 0; n < 4; ++n) {
        const int eg = ie * 256 + wc * 64 + n * 16 + (lane & 15);
        orow[eg] = acc[m][n][r] * il;
      }
    }
  }
}

extern "C" void kernel_launch(void* const* d_in, const int* in_sizes, int n_in,
                              void* d_out, int out_size, void* d_ws, size_t ws_size,
                              hipStream_t stream)
{
  const float* x    = (const float*)d_in[0];  // [8, 2048, 1024]
  const float* W    = (const float*)d_in[1];  // [3072, 1024]
  const float* bias = (const float*)d_in[2];  // [3072]
  float* out = (float*)d_out;

  char* ws = (char*)d_ws;
  const size_t ALIGN = 256;
  auto up = [&](size_t v) { return (v + ALIGN - 1) & ~(ALIGN - 1); };

  const size_t szWb = up((size_t)3 * E_DIM * E_DIM * 2);
  const size_t szX  = up((size_t)T_DIM * E_DIM * 2);
  const size_t szS  = up((size_t)T_DIM * T_DIM * 4);
  const size_t szP  = up((size_t)T_DIM * T_DIM * 2);
  const size_t szI  = up((size_t)T_DIM * 4);
  const size_t perB = 4 * szX + szS + szP + szI;

  int nb = 1;
  for (int cand = NBATCH; cand >= 1; --cand) {
    if (szWb + (size_t)cand * perB <= ws_size) { nb = cand; break; }
  }

  u16* Wb = (u16*)ws;
  {
    int n4 = 3 * E_DIM * E_DIM / 4;
    k_cvt<<<(n4 + 255) / 256, 256, 0, stream>>>(W, Wb, n4);
  }

  for (int b0 = 0; b0 < NBATCH; b0 += nb) {
    const int nbc = (NBATCH - b0 < nb) ? (NBATCH - b0) : nb;
    size_t o = szWb;
    u16* Xb    = (u16*)(ws + o);  o += (size_t)nbc * szX;
    u16* Qb    = (u16*)(ws + o);  o += (size_t)nbc * szX;
    u16* Kb    = (u16*)(ws + o);  o += (size_t)nbc * szX;
    u16* Vt    = (u16*)(ws + o);  o += (size_t)nbc * szX;
    float* S   = (float*)(ws + o); o += (size_t)nbc * szS;
    u16* P     = (u16*)(ws + o);  o += (size_t)nbc * szP;
    float* inv = (float*)(ws + o); o += (size_t)nbc * szI;

    {
      int n4 = nbc * T_DIM * E_DIM / 4;
      k_cvt<<<(n4 + 255) / 256, 256, 0, stream>>>(x + (size_t)b0 * T_DIM * E_DIM, Xb, n4);
    }
    k_qkv<<<dim3(96 * nbc), 512, 0, stream>>>(Xb, Wb, bias, Qb, Kb, Vt);
    k_scores<<<dim3(36 * nbc), 512, 0, stream>>>(Qb, Kb, S);
    k_stats<<<nbc * (T_DIM / 4), 256, 0, stream>>>(S, P, inv);
    k_pv<<<dim3(32 * nbc), 512, 0, stream>>>(P, Vt, inv, out, b0);
  }
}

// Round 4
// 397.861 us; speedup vs baseline: 1.0030x; 1.0030x over previous
//
#include <hip/hip_runtime.h>

typedef unsigned short u16;
typedef unsigned int u32;
typedef __attribute__((ext_vector_type(4))) float f32x4;
typedef __attribute__((ext_vector_type(8))) short bf16x8;

#define T_DIM 2048
#define E_DIM 1024
#define NBATCH 8
#define BK64 64
#define TILEB 65536   // per K-tile buffer: A 32KB + B 32KB

struct alignas(8)  U16x4 { u16 x, y, z, w; };
struct alignas(16) F32x4 { float x, y, z, w; };

__device__ __forceinline__ u16 f2bf(float f) {
  u32 u = __float_as_uint(f);
  u += 0x7FFFu + ((u >> 16) & 1u);
  return (u16)(u >> 16);
}

__device__ __forceinline__ void gld16(u16* lds, const u16* g) {
  __builtin_amdgcn_global_load_lds((const __attribute__((address_space(1))) void*)g,
                                   (__attribute__((address_space(3))) void*)lds, 16, 0, 0);
}

// 128-B rows: bank bits [6:4] ^= row bits [2:0]. Involution, 16B-uniform.
// Read pattern (16 lanes x consecutive rows, fixed col) -> 8 lanes per 4-bank
// group = ds_read_b128 floor. Applied to BOTH stage-source and read addrs.
__device__ __forceinline__ u32 swz7(u32 x) { return x ^ (((x >> 7) & 7u) << 4); }

// Bijective XCD-aware block remap (m204 form).
__device__ __forceinline__ int xcd_swz(int orig, int nwg) {
  int q = nwg >> 3, r = nwg & 7;
  int x = orig & 7, l = orig >> 3;
  return (x < r ? x * (q + 1) : r * (q + 1) + (x - r) * q) + l;
}

#define LGKM0_PIN() do { asm volatile("s_waitcnt lgkmcnt(0)" ::: "memory"); \
                         __builtin_amdgcn_sched_barrier(0); } while (0)

// ---------------------------------------------------------------------------
// C = A * B^T, 256x256 tile, 512 threads (8 waves = 2M x 4N), BK=64.
// Double-buffered LDS (128 KiB), 4 enforced phases per K-tile, counted-overlap
// vmcnt(0) at ph4 (loads issued at ph1 -> ~3 MFMA phases of slack).
// ---------------------------------------------------------------------------
__device__ __forceinline__ void gemm256(const u16* __restrict__ A, const u16* __restrict__ B,
                                        int lda, int ldb, int nK, char* lds0, f32x4 acc[8][4])
{
  const int tid = threadIdx.x, lane = tid & 63, wave = tid >> 6;
  const int wr = wave >> 2, wc = wave & 3;

  // Stage mapping: linear LDS dest L, global source pre-swizzled by swz7
  // (involution: reader at swz7(g) sees logical byte g).
  const u16* srcA[4]; const u16* srcB[4];
#pragma unroll
  for (int c = 0; c < 4; ++c) {
    u32 L = (u32)(c * 8192 + tid * 16);
    u32 g = swz7(L);
    srcA[c] = A + (size_t)(g >> 7) * lda + ((g & 127u) >> 1);
    srcB[c] = B + (size_t)(g >> 7) * ldb + ((g & 127u) >> 1);
  }

  auto stage8 = [&](int t) {
    char* buf = lds0 + (size_t)(t & 1) * TILEB;
    const u32 base = (u32)(tid * 16);
#pragma unroll
    for (int c = 0; c < 4; ++c)
      gld16((u16*)(buf + c * 8192 + base), srcA[c] + t * BK64);
#pragma unroll
    for (int c = 0; c < 4; ++c)
      gld16((u16*)(buf + 32768 + c * 8192 + base), srcB[c] + t * BK64);
  };

  // Read offsets: byte = row*128 + ks*64 + (lane>>4)*16, row = tile_row + (lane&15).
  const u32 lb = (u32)(lane & 15) * 128u + (u32)(lane >> 4) * 16u;
  u32 aoff[2][8], boff[2][4];
#pragma unroll
  for (int ks = 0; ks < 2; ++ks) {
#pragma unroll
    for (int m = 0; m < 8; ++m)
      aoff[ks][m] = swz7((u32)((wr * 128 + m * 16) * 128) + lb + (u32)(ks * 64));
#pragma unroll
    for (int n = 0; n < 4; ++n)
      boff[ks][n] = 32768u + swz7((u32)((wc * 64 + n * 16) * 128) + lb + (u32)(ks * 64));
  }

  stage8(0);
  asm volatile("s_waitcnt vmcnt(0)" ::: "memory");
  __builtin_amdgcn_s_barrier();

  bf16x8 a[2][4], bA[2][2], bB[2][2];

  for (int t = 0; t < nK; ++t) {
    const char* buf = lds0 + (size_t)(t & 1) * TILEB;

    // ---- phase 1: reads a(m0-3) + b(n0-1); stage next K-tile ----
#pragma unroll
    for (int ks = 0; ks < 2; ++ks) {
#pragma unroll
      for (int j = 0; j < 4; ++j) a[ks][j] = *(const bf16x8*)(buf + aoff[ks][j]);
#pragma unroll
      for (int n = 0; n < 2; ++n) bA[ks][n] = *(const bf16x8*)(buf + boff[ks][n]);
    }
    if (t + 1 < nK) stage8(t + 1);
    __builtin_amdgcn_s_barrier();
    LGKM0_PIN();
    __builtin_amdgcn_s_setprio(1);
#pragma unroll
    for (int ks = 0; ks < 2; ++ks)
#pragma unroll
      for (int j = 0; j < 4; ++j)
#pragma unroll
        for (int n = 0; n < 2; ++n)
          acc[j][n] = __builtin_amdgcn_mfma_f32_16x16x32_bf16(a[ks][j], bA[ks][n], acc[j][n], 0, 0, 0);
    __builtin_amdgcn_s_setprio(0);
    __builtin_amdgcn_sched_barrier(0);
    __builtin_amdgcn_s_barrier();

    // ---- phase 2: reads b(n2-3) ----
#pragma unroll
    for (int ks = 0; ks < 2; ++ks)
#pragma unroll
      for (int n = 0; n < 2; ++n) bB[ks][n] = *(const bf16x8*)(buf + boff[ks][2 + n]);
    __builtin_amdgcn_s_barrier();
    LGKM0_PIN();
    __builtin_amdgcn_s_setprio(1);
#pragma unroll
    for (int ks = 0; ks < 2; ++ks)
#pragma unroll
      for (int j = 0; j < 4; ++j)
#pragma unroll
        for (int n = 0; n < 2; ++n)
          acc[j][2 + n] = __builtin_amdgcn_mfma_f32_16x16x32_bf16(a[ks][j], bB[ks][n], acc[j][2 + n], 0, 0, 0);
    __builtin_amdgcn_s_setprio(0);
    __builtin_amdgcn_sched_barrier(0);
    __builtin_amdgcn_s_barrier();

    // ---- phase 3: reads a(m4-7); MFMA vs b(n0-1) still in regs ----
#pragma unroll
    for (int ks = 0; ks < 2; ++ks)
#pragma unroll
      for (int j = 0; j < 4; ++j) a[ks][j] = *(const bf16x8*)(buf + aoff[ks][4 + j]);
    __builtin_amdgcn_s_barrier();
    LGKM0_PIN();
    __builtin_amdgcn_s_setprio(1);
#pragma unroll
    for (int ks = 0; ks < 2; ++ks)
#pragma unroll
      for (int j = 0; j < 4; ++j)
#pragma unroll
        for (int n = 0; n < 2; ++n)
          acc[4 + j][n] = __builtin_amdgcn_mfma_f32_16x16x32_bf16(a[ks][j], bA[ks][n], acc[4 + j][n], 0, 0, 0);
    __builtin_amdgcn_s_setprio(0);
    __builtin_amdgcn_sched_barrier(0);
    __builtin_amdgcn_s_barrier();

    // ---- phase 4: no reads; drain stage (issued 3 phases ago) then MFMA ----
    asm volatile("s_waitcnt vmcnt(0)" ::: "memory");
    __builtin_amdgcn_s_barrier();
    __builtin_amdgcn_s_setprio(1);
#pragma unroll
    for (int ks = 0; ks < 2; ++ks)
#pragma unroll
      for (int j = 0; j < 4; ++j)
#pragma unroll
        for (int n = 0; n < 2; ++n)
          acc[4 + j][2 + n] = __builtin_amdgcn_mfma_f32_16x16x32_bf16(a[ks][j], bB[ks][n], acc[4 + j][2 + n], 0, 0, 0);
    __builtin_amdgcn_s_setprio(0);
    __builtin_amdgcn_sched_barrier(0);
    __builtin_amdgcn_s_barrier();
  }
}

// fp32 -> bf16 convert, 4 elems/thread
__global__ __launch_bounds__(256) void k_cvt(const float* __restrict__ in, u16* __restrict__ out, int n4)
{
  int i = blockIdx.x * 256 + threadIdx.x;
  if (i >= n4) return;
  F32x4 v = *(const F32x4*)&in[(size_t)i * 4];
  U16x4 o;
  o.x = f2bf(v.x); o.y = f2bf(v.y); o.z = f2bf(v.z); o.w = f2bf(v.w);
  *(U16x4*)&out[(size_t)i * 4] = o;
}

// QKV projection: [M=nbc*T, 3E] = Xb * Wb^T + bias. Q,K row-major bf16; V transposed.
__global__ __launch_bounds__(512, 2) void k_qkv(const u16* __restrict__ Xb, const u16* __restrict__ Wb,
                                                const float* __restrict__ bias,
                                                u16* __restrict__ Q, u16* __restrict__ Kmat,
                                                u16* __restrict__ Vt)
{
  __shared__ __align__(16) char lds[2 * TILEB];
  const int wg = xcd_swz(blockIdx.x, gridDim.x);
  const int my = wg / 12, nx = wg % 12;
  const int m0 = my * 256, n0 = nx * 256;
  const int tid = threadIdx.x, lane = tid & 63, wave = tid >> 6;
  const int wr = wave >> 2, wc = wave & 3;
  f32x4 acc[8][4] = {};
  gemm256(Xb + (size_t)m0 * E_DIM, Wb + (size_t)n0 * E_DIM, E_DIM, E_DIM, E_DIM / BK64, lds, acc);

  const int region = nx >> 2;  // 0=Q 1=K 2=V (uniform per block)
#pragma unroll
  for (int n = 0; n < 4; ++n) {
    const int ng = n0 + wc * 64 + n * 16 + (lane & 15);
    const float bn = bias[ng];
    const int nl = ng & (E_DIM - 1);
#pragma unroll
    for (int m = 0; m < 8; ++m) {
      const int mg0 = m0 + wr * 128 + m * 16 + ((lane >> 4) << 2);
      if (region < 2) {
        u16* dst = region ? Kmat : Q;
#pragma unroll
        for (int r = 0; r < 4; ++r)
          dst[(size_t)(mg0 + r) * E_DIM + nl] = f2bf(acc[m][n][r] + bn);
      } else {
        const int bl = mg0 >> 11;            // chunk-local batch
        const int t0 = mg0 & (T_DIM - 1);
        U16x4 pk;
        pk.x = f2bf(acc[m][n][0] + bn);
        pk.y = f2bf(acc[m][n][1] + bn);
        pk.z = f2bf(acc[m][n][2] + bn);
        pk.w = f2bf(acc[m][n][3] + bn);
        *(U16x4*)&Vt[((size_t)bl * E_DIM + nl) * T_DIM + t0] = pk;
      }
    }
  }
}

// Causal score tiles (256x256): S = Q*K^T * scale (fp32), masked = -1e30
__global__ __launch_bounds__(512, 2) void k_scores(const u16* __restrict__ Q, const u16* __restrict__ Kmat,
                                                   float* __restrict__ S)
{
  __shared__ __align__(16) char lds[2 * TILEB];
  const int wg = xcd_swz(blockIdx.x, gridDim.x);
  const int b = wg / 36;
  const int ti = wg % 36;
  int iq = 0;
  while ((iq + 1) * (iq + 2) / 2 <= ti) ++iq;
  const int ik = ti - iq * (iq + 1) / 2;
  const int tid = threadIdx.x, lane = tid & 63, wave = tid >> 6;
  const int wr = wave >> 2, wc = wave & 3;
  f32x4 acc[8][4] = {};
  const u16* Qp = Q    + (size_t)b * T_DIM * E_DIM + (size_t)iq * 256 * E_DIM;
  const u16* Kp = Kmat + (size_t)b * T_DIM * E_DIM + (size_t)ik * 256 * E_DIM;
  gemm256(Qp, Kp, E_DIM, E_DIM, E_DIM / BK64, lds, acc);

  float* Sb = S + (size_t)b * T_DIM * T_DIM;
  const float scale = 0.03125f;  // 1/sqrt(1024)
#pragma unroll
  for (int n = 0; n < 4; ++n) {
    const int kg = ik * 256 + wc * 64 + n * 16 + (lane & 15);
#pragma unroll
    for (int m = 0; m < 8; ++m) {
      const int qg0 = iq * 256 + wr * 128 + m * 16 + ((lane >> 4) << 2);
#pragma unroll
      for (int r = 0; r < 4; ++r) {
        const int qg = qg0 + r;
        Sb[(size_t)qg * T_DIM + kg] = (kg <= qg) ? acc[m][n][r] * scale : -1e30f;
      }
    }
  }
}

// Row softmax stats: one wave per row; 256-tile-granular causal prefix.
__global__ __launch_bounds__(256) void k_stats(const float* __restrict__ S, u16* __restrict__ P,
                                               float* __restrict__ invl)
{
  const int wave = threadIdx.x >> 6, lane = threadIdx.x & 63;
  const int rg = blockIdx.x * 4 + wave;           // chunk-local row
  const int bl = rg >> 11, q = rg & (T_DIM - 1);
  const float* row = S + (size_t)bl * T_DIM * T_DIM + (size_t)q * T_DIM;
  u16* prow       = P + (size_t)bl * T_DIM * T_DIM + (size_t)q * T_DIM;
  const int Cend = ((q >> 8) + 1) << 8;

  float m = -3.4e38f;
  for (int c = lane * 4; c < Cend; c += 256) {
    F32x4 v = *(const F32x4*)&row[c];
    m = fmaxf(m, fmaxf(fmaxf(v.x, v.y), fmaxf(v.z, v.w)));
  }
#pragma unroll
  for (int off = 32; off; off >>= 1) m = fmaxf(m, __shfl_xor(m, off, 64));

  float l = 0.f;
  for (int c = lane * 4; c < Cend; c += 256) {
    F32x4 v = *(const F32x4*)&row[c];
    float e0 = __expf(v.x - m), e1 = __expf(v.y - m), e2 = __expf(v.z - m), e3 = __expf(v.w - m);
    l += e0 + e1 + e2 + e3;
    U16x4 pk; pk.x = f2bf(e0); pk.y = f2bf(e1); pk.z = f2bf(e2); pk.w = f2bf(e3);
    *(U16x4*)&prow[c] = pk;
  }
#pragma unroll
  for (int off = 32; off; off >>= 1) l += __shfl_xor(l, off, 64);
  if (lane == 0) invl[rg] = 1.f / l;
}

// PV: Y[q,e] = (1/l_q) * sum_k P[q,k] * Vt[e,k] over causal k prefix. fp32 out.
__global__ __launch_bounds__(512, 2) void k_pv(const u16* __restrict__ P, const u16* __restrict__ Vt,
                                               const float* __restrict__ invl, float* __restrict__ out,
                                               int batch0)
{
  __shared__ __align__(16) char lds[2 * TILEB];
  const int wg = xcd_swz(blockIdx.x, gridDim.x);
  const int bl = wg >> 5, rr = wg & 31;
  const int iq = rr >> 2, ie = rr & 3;
  const int tid = threadIdx.x, lane = tid & 63, wave = tid >> 6;
  const int wr = wave >> 2, wc = wave & 3;
  f32x4 acc[8][4] = {};
  const u16* Ap = P  + (size_t)bl * T_DIM * T_DIM + (size_t)iq * 256 * T_DIM;
  const u16* Bp = Vt + (size_t)bl * E_DIM * T_DIM + (size_t)ie * 256 * T_DIM;
  gemm256(Ap, Bp, T_DIM, T_DIM, (iq + 1) * 4, lds, acc);

#pragma unroll
  for (int m = 0; m < 8; ++m) {
    const int qg0 = iq * 256 + wr * 128 + m * 16 + ((lane >> 4) << 2);
#pragma unroll
    for (int r = 0; r < 4; ++r) {
      const int qg = qg0 + r;
      const float il = invl[bl * T_DIM + qg];
      float* orow = out + ((size_t)(batch0 + bl) * T_DIM + qg) * E_DIM;
#pragma unroll
      for (int n = 0; n < 4; ++n) {
        const int eg = ie * 256 + wc * 64 + n * 16 + (lane & 15);
        orow[eg] = acc[m][n][r] * il;
      }
    }
  }
}

extern "C" void kernel_launch(void* const* d_in, const int* in_sizes, int n_in,
                              void* d_out, int out_size, void* d_ws, size_t ws_size,
                              hipStream_t stream)
{
  const float* x    = (const float*)d_in[0];  // [8, 2048, 1024]
  const float* W    = (const float*)d_in[1];  // [3072, 1024]
  const float* bias = (const float*)d_in[2];  // [3072]
  float* out = (float*)d_out;

  char* ws = (char*)d_ws;
  const size_t ALIGN = 256;
  auto up = [&](size_t v) { return (v + ALIGN - 1) & ~(ALIGN - 1); };

  const size_t szWb = up((size_t)3 * E_DIM * E_DIM * 2);
  const size_t szX  = up((size_t)T_DIM * E_DIM * 2);
  const size_t szS  = up((size_t)T_DIM * T_DIM * 4);
  const size_t szP  = up((size_t)T_DIM * T_DIM * 2);
  const size_t szI  = up((size_t)T_DIM * 4);
  const size_t perB = 4 * szX + szS + szP + szI;

  int nb = 1;
  for (int cand = NBATCH; cand >= 1; --cand) {
    if (szWb + (size_t)cand * perB <= ws_size) { nb = cand; break; }
  }

  u16* Wb = (u16*)ws;
  {
    int n4 = 3 * E_DIM * E_DIM / 4;
    k_cvt<<<(n4 + 255) / 256, 256, 0, stream>>>(W, Wb, n4);
  }

  for (int b0 = 0; b0 < NBATCH; b0 += nb) {
    const int nbc = (NBATCH - b0 < nb) ? (NBATCH - b0) : nb;
    size_t o = szWb;
    u16* Xb    = (u16*)(ws + o);  o += (size_t)nbc * szX;
    u16* Qb    = (u16*)(ws + o);  o += (size_t)nbc * szX;
    u16* Kb    = (u16*)(ws + o);  o += (size_t)nbc * szX;
    u16* Vt    = (u16*)(ws + o);  o += (size_t)nbc * szX;
    float* S   = (float*)(ws + o); o += (size_t)nbc * szS;
    u16* P     = (u16*)(ws + o);  o += (size_t)nbc * szP;
    float* inv = (float*)(ws + o); o += (size_t)nbc * szI;

    {
      int n4 = nbc * T_DIM * E_DIM / 4;
      k_cvt<<<(n4 + 255) / 256, 256, 0, stream>>>(x + (size_t)b0 * T_DIM * E_DIM, Xb, n4);
    }
    k_qkv<<<dim3(96 * nbc), 512, 0, stream>>>(Xb, Wb, bias, Qb, Kb, Vt);
    k_scores<<<dim3(36 * nbc), 512, 0, stream>>>(Qb, Kb, S);
    k_stats<<<nbc * (T_DIM / 4), 256, 0, stream>>>(S, P, inv);
    k_pv<<<dim3(32 * nbc), 512, 0, stream>>>(P, Vt, inv, out, b0);
  }
}

// Round 5
// 313.230 us; speedup vs baseline: 1.2739x; 1.2702x over previous
//
#include <hip/hip_runtime.h>

typedef unsigned short u16;
typedef unsigned int u32;
typedef __attribute__((ext_vector_type(4))) float f32x4;
typedef __attribute__((ext_vector_type(8))) short bf16x8;

#define T_DIM 2048
#define E_DIM 1024
#define NBATCH 8
#define BK64 64
#define TILEB 65536   // per K-tile buffer: A 32KB + B 32KB

struct alignas(8)  U16x4 { u16 x, y, z, w; };
struct alignas(16) F32x4 { float x, y, z, w; };

__device__ __forceinline__ u16 f2bf(float f) {
  u32 u = __float_as_uint(f);
  u += 0x7FFFu + ((u >> 16) & 1u);
  return (u16)(u >> 16);
}

__device__ __forceinline__ void gld16(u16* lds, const u16* g) {
  __builtin_amdgcn_global_load_lds((const __attribute__((address_space(1))) void*)g,
                                   (__attribute__((address_space(3))) void*)lds, 16, 0, 0);
}

// 128-B rows: bank bits [6:4] ^= row bits [2:0]. Involution, 16B-uniform.
__device__ __forceinline__ u32 swz7(u32 x) { return x ^ (((x >> 7) & 7u) << 4); }
// 256-B rows variant (V transpose tile): bits [6:4] ^= bits [10:8].
__device__ __forceinline__ u32 swzV(u32 x) { return x ^ (((x >> 8) & 7u) << 4); }

// Bijective XCD-aware block remap (m204 form).
__device__ __forceinline__ int xcd_swz(int orig, int nwg) {
  int q = nwg >> 3, r = nwg & 7;
  int x = orig & 7, l = orig >> 3;
  return (x < r ? x * (q + 1) : r * (q + 1) + (x - r) * q) + l;
}

#define LGKM0_PIN() do { asm volatile("s_waitcnt lgkmcnt(0)" ::: "memory"); \
                         __builtin_amdgcn_sched_barrier(0); } while (0)

// ---------------------------------------------------------------------------
// C = A * B^T, 256x256 tile, 512 threads (8 waves = 2M x 4N), BK=64.
// Double-buffered LDS (128 KiB), 4 enforced phases per K-tile. (Round-4 core:
// verified conflict-free; schedule variants measured equivalent.)
// ---------------------------------------------------------------------------
__device__ __forceinline__ void gemm256(const u16* __restrict__ A, const u16* __restrict__ B,
                                        int lda, int ldb, int nK, char* lds0, f32x4 acc[8][4])
{
  const int tid = threadIdx.x, lane = tid & 63, wave = tid >> 6;
  const int wr = wave >> 2, wc = wave & 3;

  const u16* srcA[4]; const u16* srcB[4];
#pragma unroll
  for (int c = 0; c < 4; ++c) {
    u32 L = (u32)(c * 8192 + tid * 16);
    u32 g = swz7(L);
    srcA[c] = A + (size_t)(g >> 7) * lda + ((g & 127u) >> 1);
    srcB[c] = B + (size_t)(g >> 7) * ldb + ((g & 127u) >> 1);
  }

  auto stage8 = [&](int t) {
    char* buf = lds0 + (size_t)(t & 1) * TILEB;
    const u32 base = (u32)(tid * 16);
#pragma unroll
    for (int c = 0; c < 4; ++c)
      gld16((u16*)(buf + c * 8192 + base), srcA[c] + t * BK64);
#pragma unroll
    for (int c = 0; c < 4; ++c)
      gld16((u16*)(buf + 32768 + c * 8192 + base), srcB[c] + t * BK64);
  };

  const u32 lb = (u32)(lane & 15) * 128u + (u32)(lane >> 4) * 16u;
  u32 aoff[2][8], boff[2][4];
#pragma unroll
  for (int ks = 0; ks < 2; ++ks) {
#pragma unroll
    for (int m = 0; m < 8; ++m)
      aoff[ks][m] = swz7((u32)((wr * 128 + m * 16) * 128) + lb + (u32)(ks * 64));
#pragma unroll
    for (int n = 0; n < 4; ++n)
      boff[ks][n] = 32768u + swz7((u32)((wc * 64 + n * 16) * 128) + lb + (u32)(ks * 64));
  }

  stage8(0);
  asm volatile("s_waitcnt vmcnt(0)" ::: "memory");
  __builtin_amdgcn_s_barrier();

  bf16x8 a[2][4], bA[2][2], bB[2][2];

  for (int t = 0; t < nK; ++t) {
    const char* buf = lds0 + (size_t)(t & 1) * TILEB;

    // phase 1
#pragma unroll
    for (int ks = 0; ks < 2; ++ks) {
#pragma unroll
      for (int j = 0; j < 4; ++j) a[ks][j] = *(const bf16x8*)(buf + aoff[ks][j]);
#pragma unroll
      for (int n = 0; n < 2; ++n) bA[ks][n] = *(const bf16x8*)(buf + boff[ks][n]);
    }
    if (t + 1 < nK) stage8(t + 1);
    __builtin_amdgcn_s_barrier();
    LGKM0_PIN();
    __builtin_amdgcn_s_setprio(1);
#pragma unroll
    for (int ks = 0; ks < 2; ++ks)
#pragma unroll
      for (int j = 0; j < 4; ++j)
#pragma unroll
        for (int n = 0; n < 2; ++n)
          acc[j][n] = __builtin_amdgcn_mfma_f32_16x16x32_bf16(a[ks][j], bA[ks][n], acc[j][n], 0, 0, 0);
    __builtin_amdgcn_s_setprio(0);
    __builtin_amdgcn_sched_barrier(0);
    __builtin_amdgcn_s_barrier();

    // phase 2
#pragma unroll
    for (int ks = 0; ks < 2; ++ks)
#pragma unroll
      for (int n = 0; n < 2; ++n) bB[ks][n] = *(const bf16x8*)(buf + boff[ks][2 + n]);
    __builtin_amdgcn_s_barrier();
    LGKM0_PIN();
    __builtin_amdgcn_s_setprio(1);
#pragma unroll
    for (int ks = 0; ks < 2; ++ks)
#pragma unroll
      for (int j = 0; j < 4; ++j)
#pragma unroll
        for (int n = 0; n < 2; ++n)
          acc[j][2 + n] = __builtin_amdgcn_mfma_f32_16x16x32_bf16(a[ks][j], bB[ks][n], acc[j][2 + n], 0, 0, 0);
    __builtin_amdgcn_s_setprio(0);
    __builtin_amdgcn_sched_barrier(0);
    __builtin_amdgcn_s_barrier();

    // phase 3
#pragma unroll
    for (int ks = 0; ks < 2; ++ks)
#pragma unroll
      for (int j = 0; j < 4; ++j) a[ks][j] = *(const bf16x8*)(buf + aoff[ks][4 + j]);
    __builtin_amdgcn_s_barrier();
    LGKM0_PIN();
    __builtin_amdgcn_s_setprio(1);
#pragma unroll
    for (int ks = 0; ks < 2; ++ks)
#pragma unroll
      for (int j = 0; j < 4; ++j)
#pragma unroll
        for (int n = 0; n < 2; ++n)
          acc[4 + j][n] = __builtin_amdgcn_mfma_f32_16x16x32_bf16(a[ks][j], bA[ks][n], acc[4 + j][n], 0, 0, 0);
    __builtin_amdgcn_s_setprio(0);
    __builtin_amdgcn_sched_barrier(0);
    __builtin_amdgcn_s_barrier();

    // phase 4
    asm volatile("s_waitcnt vmcnt(0)" ::: "memory");
    __builtin_amdgcn_s_barrier();
    __builtin_amdgcn_s_setprio(1);
#pragma unroll
    for (int ks = 0; ks < 2; ++ks)
#pragma unroll
      for (int j = 0; j < 4; ++j)
#pragma unroll
        for (int n = 0; n < 2; ++n)
          acc[4 + j][2 + n] = __builtin_amdgcn_mfma_f32_16x16x32_bf16(a[ks][j], bB[ks][n], acc[4 + j][2 + n], 0, 0, 0);
    __builtin_amdgcn_s_setprio(0);
    __builtin_amdgcn_sched_barrier(0);
    __builtin_amdgcn_s_barrier();
  }
}

// fp32 -> bf16 convert
__global__ __launch_bounds__(256) void k_cvt(const float* __restrict__ in, u16* __restrict__ out, int n4)
{
  int i = blockIdx.x * 256 + threadIdx.x;
  if (i >= n4) return;
  F32x4 v = *(const F32x4*)&in[(size_t)i * 4];
  U16x4 o;
  o.x = f2bf(v.x); o.y = f2bf(v.y); o.z = f2bf(v.z); o.w = f2bf(v.w);
  *(U16x4*)&out[(size_t)i * 4] = o;
}

// QKV projection. Per-XCD 2D supertile raster; Vt written via LDS transpose.
__global__ __launch_bounds__(512, 2) void k_qkv(const u16* __restrict__ Xb, const u16* __restrict__ Wb,
                                                const float* __restrict__ bias,
                                                u16* __restrict__ Q, u16* __restrict__ Kmat,
                                                u16* __restrict__ Vt)
{
  __shared__ __align__(16) char lds[2 * TILEB];
  int my, nx;
  if (gridDim.x == 768) {
    // wg -> XCD = wg&7 (HW round-robin); tau enumerates this XCD's 96 tiles
    // in L2-friendly supertiles (concurrent footprint ~6MB vs 10MB).
    const int x = blockIdx.x & 7, tau = blockIdx.x >> 3;
    int my_l;
    if (tau < 64) { const int st = tau >> 5, w = tau & 31; my_l = st * 4 + (w >> 3); nx = w & 7; }
    else          { const int w = tau - 64; my_l = w >> 2; nx = 8 + (w & 3); }
    my = x * 8 + my_l;
  } else {
    const int wg = xcd_swz(blockIdx.x, gridDim.x);
    my = wg / 12; nx = wg % 12;
  }
  const int m0 = my * 256, n0 = nx * 256;
  const int tid = threadIdx.x, lane = tid & 63, wave = tid >> 6;
  const int wr = wave >> 2, wc = wave & 3;
  f32x4 acc[8][4] = {};
  gemm256(Xb + (size_t)m0 * E_DIM, Wb + (size_t)n0 * E_DIM, E_DIM, E_DIM, E_DIM / BK64, lds, acc);

  const int region = nx >> 2;  // 0=Q 1=K 2=V
  if (region < 2) {
    u16* dst = region ? Kmat : Q;
#pragma unroll
    for (int n = 0; n < 4; ++n) {
      const int ng = n0 + wc * 64 + n * 16 + (lane & 15);
      const float bn = bias[ng];
      const int nl = ng & (E_DIM - 1);
#pragma unroll
      for (int m = 0; m < 8; ++m) {
        const int mg0 = m0 + wr * 128 + m * 16 + ((lane >> 4) << 2);
#pragma unroll
        for (int r = 0; r < 4; ++r)
          dst[(size_t)(mg0 + r) * E_DIM + nl] = f2bf(acc[m][n][r] + bn);
      }
    }
  } else {
    // V: transpose via per-wave LDS tile (64 e x 128 t bf16 = 16KB), then
    // coalesced 256B-row writes. gemm's trailing barrier makes lds free.
    char* wslice = lds + wave * 16384;
#pragma unroll
    for (int n = 0; n < 4; ++n) {
      const int ng = n0 + wc * 64 + n * 16 + (lane & 15);
      const float bn = bias[ng];
#pragma unroll
      for (int m = 0; m < 8; ++m) {
#pragma unroll
        for (int rp = 0; rp < 4; rp += 2) {
          u32 w = (u32)f2bf(acc[m][n][rp] + bn) | ((u32)f2bf(acc[m][n][rp + 1] + bn) << 16);
          u32 eb = swzV((u32)((n * 16 + (lane & 15)) * 256 + (m * 16 + ((lane >> 4) << 2) + rp) * 2));
          *(u32*)(wslice + eb) = w;
        }
      }
    }
    // no barrier needed: each wave reads only its own slice
    asm volatile("s_waitcnt lgkmcnt(0)" ::: "memory");
    const int bl = m0 >> 11;
    const int t_base = (m0 & (T_DIM - 1)) + wr * 128;
    const int nl_base = (n0 & (E_DIM - 1)) + wc * 64;
    const int t8 = (lane & 15) * 8;
#pragma unroll
    for (int k = 0; k < 16; ++k) {
      const int e_loc = (lane >> 4) + k * 4;
      bf16x8 v = *(const bf16x8*)(wslice + swzV((u32)(e_loc * 256 + t8 * 2)));
      *(bf16x8*)&Vt[((size_t)bl * E_DIM + nl_base + e_loc) * T_DIM + t_base + t8] = v;
    }
  }
}

// Fused causal scores + per-chunk softmax prep.
// Writes P' = exp(S - m_chunk) bf16 (0 where masked), mc/lc per (row, chunk).
__global__ __launch_bounds__(512, 2) void k_sp(const u16* __restrict__ Q, const u16* __restrict__ Kmat,
                                               u16* __restrict__ P, float* __restrict__ mc,
                                               float* __restrict__ lc)
{
  __shared__ __align__(16) char lds[2 * TILEB];
  const int wg = xcd_swz(blockIdx.x, gridDim.x);
  const int b = wg / 36;
  const int ti = wg % 36;
  int iq = 0;
  while ((iq + 1) * (iq + 2) / 2 <= ti) ++iq;
  const int ik = ti - iq * (iq + 1) / 2;
  const int tid = threadIdx.x, lane = tid & 63, wave = tid >> 6;
  const int wr = wave >> 2, wc = wave & 3;
  f32x4 acc[8][4] = {};
  const u16* Qp = Q    + (size_t)b * T_DIM * E_DIM + (size_t)iq * 256 * E_DIM;
  const u16* Kp = Kmat + (size_t)b * T_DIM * E_DIM + (size_t)ik * 256 * E_DIM;
  gemm256(Qp, Kp, E_DIM, E_DIM, E_DIM / BK64, lds, acc);

  const float scale = 0.03125f;  // 1/sqrt(1024)
  // scale + causal mask (diag tile only)
#pragma unroll
  for (int m = 0; m < 8; ++m)
#pragma unroll
    for (int n = 0; n < 4; ++n)
#pragma unroll
      for (int r = 0; r < 4; ++r) acc[m][n][r] *= scale;
  if (ik == iq) {
#pragma unroll
    for (int n = 0; n < 4; ++n) {
      const int kg = wc * 64 + n * 16 + (lane & 15);
#pragma unroll
      for (int m = 0; m < 8; ++m) {
        const int qg0 = wr * 128 + m * 16 + ((lane >> 4) << 2);
#pragma unroll
        for (int r = 0; r < 4; ++r)
          if (kg > qg0 + r) acc[m][n][r] = -3.4e38f;
      }
    }
  }

  // per-row chunk max: within wave (64 cols) via shfl, cross-wave via LDS
  float* red  = (float*)lds;          // [4][256]
  float* red2 = (float*)lds + 1024;   // [4][256]
  float M[8][4];
#pragma unroll
  for (int m = 0; m < 8; ++m)
#pragma unroll
    for (int r = 0; r < 4; ++r) {
      float v = fmaxf(fmaxf(acc[m][0][r], acc[m][1][r]), fmaxf(acc[m][2][r], acc[m][3][r]));
#pragma unroll
      for (int off = 1; off <= 8; off <<= 1) v = fmaxf(v, __shfl_xor(v, off, 64));
      M[m][r] = v;
    }
  if ((lane & 15) == 0) {
#pragma unroll
    for (int m = 0; m < 8; ++m)
#pragma unroll
      for (int r = 0; r < 4; ++r)
        red[wc * 256 + wr * 128 + m * 16 + ((lane >> 4) << 2) + r] = M[m][r];
  }
  __syncthreads();
#pragma unroll
  for (int m = 0; m < 8; ++m)
#pragma unroll
    for (int r = 0; r < 4; ++r) {
      const int row = wr * 128 + m * 16 + ((lane >> 4) << 2) + r;
      M[m][r] = fmaxf(fmaxf(red[row], red[256 + row]), fmaxf(red[512 + row], red[768 + row]));
    }

  // exp pass: write P', accumulate row sums
  u16* Pb = P + (size_t)b * T_DIM * T_DIM;
  float Ls[8][4];
#pragma unroll
  for (int m = 0; m < 8; ++m) {
    const int qg0 = iq * 256 + wr * 128 + m * 16 + ((lane >> 4) << 2);
#pragma unroll
    for (int r = 0; r < 4; ++r) {
      float s = 0.f;
      u16* prow = Pb + (size_t)(qg0 + r) * T_DIM + ik * 256;
#pragma unroll
      for (int n = 0; n < 4; ++n) {
        float e = __expf(acc[m][n][r] - M[m][r]);
        s += e;
        prow[wc * 64 + n * 16 + (lane & 15)] = f2bf(e);
      }
#pragma unroll
      for (int off = 1; off <= 8; off <<= 1) s += __shfl_xor(s, off, 64);
      Ls[m][r] = s;
    }
  }
  if ((lane & 15) == 0) {
#pragma unroll
    for (int m = 0; m < 8; ++m)
#pragma unroll
      for (int r = 0; r < 4; ++r)
        red2[wc * 256 + wr * 128 + m * 16 + ((lane >> 4) << 2) + r] = Ls[m][r];
  }
  __syncthreads();
  if (wc == 0 && (lane & 15) == 0) {
#pragma unroll
    for (int m = 0; m < 8; ++m)
#pragma unroll
      for (int r = 0; r < 4; ++r) {
        const int row = wr * 128 + m * 16 + ((lane >> 4) << 2) + r;
        const float l = red2[row] + red2[256 + row] + red2[512 + row] + red2[768 + row];
        const size_t idx = ((size_t)b * T_DIM + iq * 256 + row) * 8 + ik;
        mc[idx] = M[m][r];
        lc[idx] = l;
      }
  }
}

// Per-row finish: fin = exp(m_last - M) / L
__global__ __launch_bounds__(256) void k_finish(const float* __restrict__ mc, const float* __restrict__ lc,
                                                float* __restrict__ fin)
{
  const int rg = blockIdx.x * 256 + threadIdx.x;   // chunk-local row (bl*2048+q)
  const int q = rg & (T_DIM - 1);
  const int C = (q >> 8) + 1;
  const float* m = mc + (size_t)rg * 8;
  const float* l = lc + (size_t)rg * 8;
  float M = -3.4e38f;
  for (int c = 0; c < C; ++c) M = fmaxf(M, m[c]);
  float L = 0.f;
  for (int c = 0; c < C; ++c) L += l[c] * __expf(m[c] - M);
  fin[rg] = __expf(m[C - 1] - M) / L;
}

// PV over causal 256-chunks with inter-chunk rescale h_c = exp(m_{c-1}-m_c).
__global__ __launch_bounds__(512, 2) void k_pv(const u16* __restrict__ P, const u16* __restrict__ Vt,
                                               const float* __restrict__ mc, const float* __restrict__ fin,
                                               float* __restrict__ out, int batch0)
{
  __shared__ __align__(16) char lds[2 * TILEB];
  const int wg = xcd_swz(blockIdx.x, gridDim.x);
  const int bl = wg >> 5, rr = wg & 31;
  const int iq = rr >> 2, ie = rr & 3;
  const int tid = threadIdx.x, lane = tid & 63, wave = tid >> 6;
  const int wr = wave >> 2, wc = wave & 3;
  f32x4 acc[8][4] = {};
  const u16* Ap = P  + (size_t)bl * T_DIM * T_DIM + (size_t)iq * 256 * T_DIM;
  const u16* Bp = Vt + (size_t)bl * E_DIM * T_DIM + (size_t)ie * 256 * T_DIM;
  const float* mrow = mc + ((size_t)bl * T_DIM + iq * 256) * 8;

  for (int c = 0; c <= iq; ++c) {
    if (c > 0) {
#pragma unroll
      for (int m = 0; m < 8; ++m) {
        const int row0 = wr * 128 + m * 16 + ((lane >> 4) << 2);
#pragma unroll
        for (int r = 0; r < 4; ++r) {
          const float h = __expf(mrow[(size_t)(row0 + r) * 8 + (c - 1)] - mrow[(size_t)(row0 + r) * 8 + c]);
#pragma unroll
          for (int n = 0; n < 4; ++n) acc[m][n][r] *= h;
        }
      }
    }
    gemm256(Ap + c * 256, Bp + c * 256, T_DIM, T_DIM, 4, lds, acc);
  }

#pragma unroll
  for (int m = 0; m < 8; ++m) {
    const int qg0 = iq * 256 + wr * 128 + m * 16 + ((lane >> 4) << 2);
#pragma unroll
    for (int r = 0; r < 4; ++r) {
      const int qg = qg0 + r;
      const float il = fin[bl * T_DIM + qg];
      float* orow = out + ((size_t)(batch0 + bl) * T_DIM + qg) * E_DIM;
#pragma unroll
      for (int n = 0; n < 4; ++n) {
        const int eg = ie * 256 + wc * 64 + n * 16 + (lane & 15);
        orow[eg] = acc[m][n][r] * il;
      }
    }
  }
}

extern "C" void kernel_launch(void* const* d_in, const int* in_sizes, int n_in,
                              void* d_out, int out_size, void* d_ws, size_t ws_size,
                              hipStream_t stream)
{
  const float* x    = (const float*)d_in[0];  // [8, 2048, 1024]
  const float* W    = (const float*)d_in[1];  // [3072, 1024]
  const float* bias = (const float*)d_in[2];  // [3072]
  float* out = (float*)d_out;

  char* ws = (char*)d_ws;
  const size_t ALIGN = 256;
  auto up = [&](size_t v) { return (v + ALIGN - 1) & ~(ALIGN - 1); };

  const size_t szWb = up((size_t)3 * E_DIM * E_DIM * 2);
  const size_t szX  = up((size_t)T_DIM * E_DIM * 2);       // bf16 [T,E] per batch
  const size_t szP  = up((size_t)T_DIM * T_DIM * 2);       // bf16 P' per batch
  const size_t szM  = up((size_t)T_DIM * 8 * 4);           // mc / lc per batch
  const size_t szI  = up((size_t)T_DIM * 4);               // fin per batch
  const size_t perB = 4 * szX + szP + 2 * szM + szI;

  int nb = 1;
  for (int cand = NBATCH; cand >= 1; --cand) {
    if (szWb + (size_t)cand * perB <= ws_size) { nb = cand; break; }
  }

  u16* Wb = (u16*)ws;
  {
    int n4 = 3 * E_DIM * E_DIM / 4;
    k_cvt<<<(n4 + 255) / 256, 256, 0, stream>>>(W, Wb, n4);
  }

  for (int b0 = 0; b0 < NBATCH; b0 += nb) {
    const int nbc = (NBATCH - b0 < nb) ? (NBATCH - b0) : nb;
    size_t o = szWb;
    u16* Xb    = (u16*)(ws + o);   o += (size_t)nbc * szX;
    u16* Qb    = (u16*)(ws + o);   o += (size_t)nbc * szX;
    u16* Kb    = (u16*)(ws + o);   o += (size_t)nbc * szX;
    u16* Vt    = (u16*)(ws + o);   o += (size_t)nbc * szX;
    u16* P     = (u16*)(ws + o);   o += (size_t)nbc * szP;
    float* mcA = (float*)(ws + o); o += (size_t)nbc * szM;
    float* lcA = (float*)(ws + o); o += (size_t)nbc * szM;
    float* fin = (float*)(ws + o); o += (size_t)nbc * szI;

    {
      int n4 = nbc * T_DIM * E_DIM / 4;
      k_cvt<<<(n4 + 255) / 256, 256, 0, stream>>>(x + (size_t)b0 * T_DIM * E_DIM, Xb, n4);
    }
    k_qkv<<<dim3(96 * nbc), 512, 0, stream>>>(Xb, Wb, bias, Qb, Kb, Vt);
    k_sp<<<dim3(36 * nbc), 512, 0, stream>>>(Qb, Kb, P, mcA, lcA);
    k_finish<<<dim3(nbc * T_DIM / 256), 256, 0, stream>>>(mcA, lcA, fin);
    k_pv<<<dim3(32 * nbc), 512, 0, stream>>>(P, Vt, mcA, fin, out, b0);
  }
}

// Round 6
// 272.588 us; speedup vs baseline: 1.4639x; 1.1491x over previous
//
#include <hip/hip_runtime.h>

typedef unsigned short u16;
typedef unsigned int u32;
typedef __attribute__((ext_vector_type(4))) float f32x4;
typedef __attribute__((ext_vector_type(8))) short bf16x8;

#define T_DIM 2048
#define E_DIM 1024
#define NBATCH 8
#define BK 32
#define BUF 32768    // one K-tile buffer: A 16KB + B 16KB
#define CORE_LDS (3 * BUF)

struct alignas(8)  U16x4 { u16 x, y, z, w; };
struct alignas(16) F32x4 { float x, y, z, w; };

__device__ __forceinline__ u16 f2bf(float f) {
  u32 u = __float_as_uint(f);
  u += 0x7FFFu + ((u >> 16) & 1u);
  return (u16)(u >> 16);
}

__device__ __forceinline__ void gld16(u16* lds, const u16* g) {
  __builtin_amdgcn_global_load_lds((const __attribute__((address_space(1))) void*)g,
                                   (__attribute__((address_space(3))) void*)lds, 16, 0, 0);
}

// Swizzle verified conflict-free in r4 (SQ_LDS_BANK_CONFLICT = 0):
// byte bits [6:4] ^= bits [9:7]. Involution, 16B-uniform.
__device__ __forceinline__ u32 swz7(u32 x) { return x ^ (((x >> 7) & 7u) << 4); }

// Bijective XCD-aware block remap (m204 form).
__device__ __forceinline__ int xcd_swz(int orig, int nwg) {
  int q = nwg >> 3, r = nwg & 7;
  int x = orig & 7, l = orig >> 3;
  return (x < r ? x * (q + 1) : r * (q + 1) + (x - r) * q) + l;
}

#define LGKM0_PIN() do { asm volatile("s_waitcnt lgkmcnt(0)" ::: "memory"); \
                         __builtin_amdgcn_sched_barrier(0); } while (0)

// ---------------------------------------------------------------------------
// C = A * B^T, 256x256 tile, 512 threads (8 waves = 2M x 4N), BK=32.
// 3 LDS buffers, staging 2 tiles ahead, ONE counted vmcnt(4) + ONE barrier
// per K-tile (vmcnt(0) only at the final tile). 2 phases/tile, 16 MFMA each.
// hook(t) runs once per tile right after the barrier (used by k_pv rescale).
// Requires nK >= 2. No trailing barrier: callers must __syncthreads() before
// reusing LDS.
// ---------------------------------------------------------------------------
template <typename HOOK>
__device__ __forceinline__ void gemm256(const u16* __restrict__ A, const u16* __restrict__ B,
                                        int lda, int ldb, int nK, char* lds0, f32x4 acc[8][4],
                                        HOOK&& hook)
{
  const int tid = threadIdx.x, lane = tid & 63, wave = tid >> 6;
  const int wr = wave >> 2, wc = wave & 3;

  // Staging: linear LDS dest, pre-swizzled global source (involution).
  const u16* sAp[2]; const u16* sBp[2];
#pragma unroll
  for (int c = 0; c < 2; ++c) {
    u32 L = (u32)(c * 8192 + tid * 16);
    u32 g = swz7(L);
    sAp[c] = A + (size_t)(g >> 6) * lda + ((g & 63u) >> 1);
    sBp[c] = B + (size_t)(g >> 6) * ldb + ((g & 63u) >> 1);
  }
  const u32 doff = (u32)tid * 16u;

  auto stageA = [&](char* buf, int t) {
#pragma unroll
    for (int c = 0; c < 2; ++c)
      gld16((u16*)(buf + c * 8192 + doff), sAp[c] + t * BK);
  };
  auto stageB = [&](char* buf, int t) {
#pragma unroll
    for (int c = 0; c < 2; ++c)
      gld16((u16*)(buf + 16384 + c * 8192 + doff), sBp[c] + t * BK);
  };

  // Swizzled read offsets (64B rows, 16B k-chunk per lane-quad).
  const u32 cb = (u32)(lane >> 4) * 16u;
  u32 aoff[8], boff[4];
#pragma unroll
  for (int m = 0; m < 8; ++m)
    aoff[m] = swz7((u32)(wr * 128 + m * 16 + (lane & 15)) * 64u + cb);
#pragma unroll
  for (int n = 0; n < 4; ++n)
    boff[n] = 16384u + swz7((u32)(wc * 64 + n * 16 + (lane & 15)) * 64u + cb);

  // Prologue: tiles 0 and 1 in flight (8 loads/thread).
  stageA(lds0, 0); stageB(lds0, 0);
  stageA(lds0 + BUF, 1); stageB(lds0 + BUF, 1);

  int bc = 0;
  bf16x8 a[4], b[4];
  for (int t = 0; t < nK; ++t) {
    char* bufR = lds0 + bc * BUF;
    int b2 = bc + 2; if (b2 >= 3) b2 -= 3;
    char* bufW = lds0 + b2 * BUF;

    // Counted wait: 4 newest loads (tile t+1) may stay in flight.
    if (t + 1 < nK) asm volatile("s_waitcnt vmcnt(4)" ::: "memory");
    else            asm volatile("s_waitcnt vmcnt(0)" ::: "memory");
    __builtin_amdgcn_s_barrier();
    __builtin_amdgcn_sched_barrier(0);

    hook(t);

    // ---- phase 1: stage A(t+2); read a[m0-3], b[n0-3]; 16 MFMA ----
    if (t + 2 < nK) stageA(bufW, t + 2);
#pragma unroll
    for (int j = 0; j < 4; ++j) a[j] = *(const bf16x8*)(bufR + aoff[j]);
#pragma unroll
    for (int n = 0; n < 4; ++n) b[n] = *(const bf16x8*)(bufR + boff[n]);
    LGKM0_PIN();
    __builtin_amdgcn_s_setprio(1);
#pragma unroll
    for (int j = 0; j < 4; ++j)
#pragma unroll
      for (int n = 0; n < 4; ++n)
        acc[j][n] = __builtin_amdgcn_mfma_f32_16x16x32_bf16(a[j], b[n], acc[j][n], 0, 0, 0);
    __builtin_amdgcn_s_setprio(0);
    __builtin_amdgcn_sched_barrier(0);

    // ---- phase 2: stage B(t+2); read a[m4-7]; 16 MFMA ----
    if (t + 2 < nK) stageB(bufW, t + 2);
#pragma unroll
    for (int j = 0; j < 4; ++j) a[j] = *(const bf16x8*)(bufR + aoff[4 + j]);
    LGKM0_PIN();
    __builtin_amdgcn_s_setprio(1);
#pragma unroll
    for (int j = 0; j < 4; ++j)
#pragma unroll
      for (int n = 0; n < 4; ++n)
        acc[4 + j][n] = __builtin_amdgcn_mfma_f32_16x16x32_bf16(a[j], b[n], acc[4 + j][n], 0, 0, 0);
    __builtin_amdgcn_s_setprio(0);
    __builtin_amdgcn_sched_barrier(0);

    bc = bc + 1 == 3 ? 0 : bc + 1;
  }
}

struct NoHook { __device__ void operator()(int) const {} };

// fp32 -> bf16 convert
__global__ __launch_bounds__(256) void k_cvt(const float* __restrict__ in, u16* __restrict__ out, int n4)
{
  int i = blockIdx.x * 256 + threadIdx.x;
  if (i >= n4) return;
  F32x4 v = *(const F32x4*)&in[(size_t)i * 4];
  U16x4 o;
  o.x = f2bf(v.x); o.y = f2bf(v.y); o.z = f2bf(v.z); o.w = f2bf(v.w);
  *(U16x4*)&out[(size_t)i * 4] = o;
}

// QKV projection: [M=nbc*T, 3E] = Xb * Wb^T + bias. Q,K row-major; Vt transposed.
__global__ __launch_bounds__(512, 2) void k_qkv(const u16* __restrict__ Xb, const u16* __restrict__ Wb,
                                                const float* __restrict__ bias,
                                                u16* __restrict__ Q, u16* __restrict__ Kmat,
                                                u16* __restrict__ Vt)
{
  __shared__ __align__(16) char lds[131072];  // core 96K; V-transpose uses 128K
  const int wg = xcd_swz(blockIdx.x, gridDim.x);
  const int my = wg / 12, nx = wg % 12;
  const int m0 = my * 256, n0 = nx * 256;
  const int tid = threadIdx.x, lane = tid & 63, wave = tid >> 6;
  const int wr = wave >> 2, wc = wave & 3;
  f32x4 acc[8][4] = {};
  gemm256(Xb + (size_t)m0 * E_DIM, Wb + (size_t)n0 * E_DIM, E_DIM, E_DIM, E_DIM / BK,
          lds, acc, NoHook{});

  const int region = nx >> 2;  // 0=Q 1=K 2=V
  if (region < 2) {
    u16* dst = region ? Kmat : Q;
#pragma unroll
    for (int n = 0; n < 4; ++n) {
      const int ng = n0 + wc * 64 + n * 16 + (lane & 15);
      const float bn = bias[ng];
      const int nl = ng & (E_DIM - 1);
#pragma unroll
      for (int m = 0; m < 8; ++m) {
        const int mg0 = m0 + wr * 128 + m * 16 + ((lane >> 4) << 2);
#pragma unroll
        for (int r = 0; r < 4; ++r)
          dst[(size_t)(mg0 + r) * E_DIM + nl] = f2bf(acc[m][n][r] + bn);
      }
    }
  } else {
    __syncthreads();  // core has no trailing barrier; protect LDS reuse
    char* wslice = lds + wave * 16384;
#pragma unroll
    for (int n = 0; n < 4; ++n) {
      const int ng = n0 + wc * 64 + n * 16 + (lane & 15);
      const float bn = bias[ng];
#pragma unroll
      for (int m = 0; m < 8; ++m) {
#pragma unroll
        for (int rp = 0; rp < 4; rp += 2) {
          u32 w = (u32)f2bf(acc[m][n][rp] + bn) | ((u32)f2bf(acc[m][n][rp + 1] + bn) << 16);
          u32 eb = (u32)((n * 16 + (lane & 15)) * 256 + (m * 16 + ((lane >> 4) << 2) + rp) * 2);
          eb ^= ((eb >> 8) & 7u) << 4;
          *(u32*)(wslice + eb) = w;
        }
      }
    }
    asm volatile("s_waitcnt lgkmcnt(0)" ::: "memory");  // own slice only
    const int bl = m0 >> 11;
    const int t_base = (m0 & (T_DIM - 1)) + wr * 128;
    const int nl_base = (n0 & (E_DIM - 1)) + wc * 64;
    const int t8 = (lane & 15) * 8;
#pragma unroll
    for (int k = 0; k < 16; ++k) {
      const int e_loc = (lane >> 4) + k * 4;
      u32 eb = (u32)(e_loc * 256 + t8 * 2);
      eb ^= ((eb >> 8) & 7u) << 4;
      bf16x8 v = *(const bf16x8*)(wslice + eb);
      *(bf16x8*)&Vt[((size_t)bl * E_DIM + nl_base + e_loc) * T_DIM + t_base + t8] = v;
    }
  }
}

// Fused causal scores + per-chunk softmax prep: P' = exp(S - m_chunk) bf16,
// mc/lc per (row, 256-chunk).
__global__ __launch_bounds__(512, 2) void k_sp(const u16* __restrict__ Q, const u16* __restrict__ Kmat,
                                               u16* __restrict__ P, float* __restrict__ mc,
                                               float* __restrict__ lc)
{
  __shared__ __align__(16) char lds[CORE_LDS];
  const int wg = xcd_swz(blockIdx.x, gridDim.x);
  const int b = wg / 36;
  const int ti = wg % 36;
  int iq = 0;
  while ((iq + 1) * (iq + 2) / 2 <= ti) ++iq;
  const int ik = ti - iq * (iq + 1) / 2;
  const int tid = threadIdx.x, lane = tid & 63, wave = tid >> 6;
  const int wr = wave >> 2, wc = wave & 3;
  f32x4 acc[8][4] = {};
  const u16* Qp = Q    + (size_t)b * T_DIM * E_DIM + (size_t)iq * 256 * E_DIM;
  const u16* Kp = Kmat + (size_t)b * T_DIM * E_DIM + (size_t)ik * 256 * E_DIM;
  gemm256(Qp, Kp, E_DIM, E_DIM, E_DIM / BK, lds, acc, NoHook{});
  __syncthreads();

  const float scale = 0.03125f;  // 1/sqrt(1024)
#pragma unroll
  for (int m = 0; m < 8; ++m)
#pragma unroll
    for (int n = 0; n < 4; ++n)
#pragma unroll
      for (int r = 0; r < 4; ++r) acc[m][n][r] *= scale;
  if (ik == iq) {
#pragma unroll
    for (int n = 0; n < 4; ++n) {
      const int kg = wc * 64 + n * 16 + (lane & 15);
#pragma unroll
      for (int m = 0; m < 8; ++m) {
        const int qg0 = wr * 128 + m * 16 + ((lane >> 4) << 2);
#pragma unroll
        for (int r = 0; r < 4; ++r)
          if (kg > qg0 + r) acc[m][n][r] = -3.4e38f;
      }
    }
  }

  float* red  = (float*)lds;          // [4][256]
  float* red2 = (float*)lds + 1024;
  float M[8][4];
#pragma unroll
  for (int m = 0; m < 8; ++m)
#pragma unroll
    for (int r = 0; r < 4; ++r) {
      float v = fmaxf(fmaxf(acc[m][0][r], acc[m][1][r]), fmaxf(acc[m][2][r], acc[m][3][r]));
#pragma unroll
      for (int off = 1; off <= 8; off <<= 1) v = fmaxf(v, __shfl_xor(v, off, 64));
      M[m][r] = v;
    }
  if ((lane & 15) == 0) {
#pragma unroll
    for (int m = 0; m < 8; ++m)
#pragma unroll
      for (int r = 0; r < 4; ++r)
        red[wc * 256 + wr * 128 + m * 16 + ((lane >> 4) << 2) + r] = M[m][r];
  }
  __syncthreads();
#pragma unroll
  for (int m = 0; m < 8; ++m)
#pragma unroll
    for (int r = 0; r < 4; ++r) {
      const int row = wr * 128 + m * 16 + ((lane >> 4) << 2) + r;
      M[m][r] = fmaxf(fmaxf(red[row], red[256 + row]), fmaxf(red[512 + row], red[768 + row]));
    }

  u16* Pb = P + (size_t)b * T_DIM * T_DIM;
  float Ls[8][4];
#pragma unroll
  for (int m = 0; m < 8; ++m) {
    const int qg0 = iq * 256 + wr * 128 + m * 16 + ((lane >> 4) << 2);
#pragma unroll
    for (int r = 0; r < 4; ++r) {
      float s = 0.f;
      u16* prow = Pb + (size_t)(qg0 + r) * T_DIM + ik * 256;
#pragma unroll
      for (int n = 0; n < 4; ++n) {
        float e = __expf(acc[m][n][r] - M[m][r]);
        s += e;
        prow[wc * 64 + n * 16 + (lane & 15)] = f2bf(e);
      }
#pragma unroll
      for (int off = 1; off <= 8; off <<= 1) s += __shfl_xor(s, off, 64);
      Ls[m][r] = s;
    }
  }
  if ((lane & 15) == 0) {
#pragma unroll
    for (int m = 0; m < 8; ++m)
#pragma unroll
      for (int r = 0; r < 4; ++r)
        red2[wc * 256 + wr * 128 + m * 16 + ((lane >> 4) << 2) + r] = Ls[m][r];
  }
  __syncthreads();
  if (wc == 0 && (lane & 15) == 0) {
#pragma unroll
    for (int m = 0; m < 8; ++m)
#pragma unroll
      for (int r = 0; r < 4; ++r) {
        const int row = wr * 128 + m * 16 + ((lane >> 4) << 2) + r;
        const float l = red2[row] + red2[256 + row] + red2[512 + row] + red2[768 + row];
        const size_t idx = ((size_t)b * T_DIM + iq * 256 + row) * 8 + ik;
        mc[idx] = M[m][r];
        lc[idx] = l;
      }
  }
}

// Per-row finish: fin = exp(m_last - M) / L
__global__ __launch_bounds__(256) void k_finish(const float* __restrict__ mc, const float* __restrict__ lc,
                                                float* __restrict__ fin)
{
  const int rg = blockIdx.x * 256 + threadIdx.x;
  const int q = rg & (T_DIM - 1);
  const int C = (q >> 8) + 1;
  const float* m = mc + (size_t)rg * 8;
  const float* l = lc + (size_t)rg * 8;
  float M = -3.4e38f;
  for (int c = 0; c < C; ++c) M = fmaxf(M, m[c]);
  float L = 0.f;
  for (int c = 0; c < C; ++c) L += l[c] * __expf(m[c] - M);
  fin[rg] = __expf(m[C - 1] - M) / L;
}

// PV: one continuous pipelined GEMM over all causal chunks, with per-row
// rescale h = exp(m_{c-1}-m_c) injected at chunk boundaries (mc via LDS).
__global__ __launch_bounds__(512, 2) void k_pv(const u16* __restrict__ P, const u16* __restrict__ Vt,
                                               const float* __restrict__ mc, const float* __restrict__ fin,
                                               float* __restrict__ out, int batch0)
{
  __shared__ __align__(16) char lds[CORE_LDS + 8192];
  const int wg = xcd_swz(blockIdx.x, gridDim.x);
  const int bl = wg >> 5, rr = wg & 31;
  const int iq = rr >> 2, ie = rr & 3;
  const int tid = threadIdx.x, lane = tid & 63, wave = tid >> 6;
  const int wr = wave >> 2, wc = wave & 3;

  // Preload mc rows for this q-tile into LDS [256][8] f32 (drained before
  // the pipeline so the core's vmcnt counting stays exact).
  float* ldsM = (float*)(lds + CORE_LDS);
  const float* mrow = mc + ((size_t)bl * T_DIM + iq * 256) * 8;
  for (int i = tid; i < 2048; i += 512) ldsM[i] = mrow[i];
  asm volatile("s_waitcnt vmcnt(0) lgkmcnt(0)" ::: "memory");
  __builtin_amdgcn_s_barrier();

  f32x4 acc[8][4] = {};
  const u16* Ap = P  + (size_t)bl * T_DIM * T_DIM + (size_t)iq * 256 * T_DIM;
  const u16* Bp = Vt + (size_t)bl * E_DIM * T_DIM + (size_t)ie * 256 * T_DIM;

  auto rescale = [&](int t) {
    if (t > 0 && (t & 7) == 0) {
      const int c = t >> 3;
#pragma unroll
      for (int m = 0; m < 8; ++m)
#pragma unroll
        for (int r = 0; r < 4; ++r) {
          const int row = wr * 128 + m * 16 + ((lane >> 4) << 2) + r;
          const float mp = ldsM[row * 8 + (c - 1)];
          const float mn = ldsM[row * 8 + c];
          const float h = __expf(mp - mn);
#pragma unroll
          for (int n = 0; n < 4; ++n) acc[m][n][r] *= h;
        }
    }
  };
  gemm256(Ap, Bp, T_DIM, T_DIM, (iq + 1) * 8, lds, acc, rescale);

#pragma unroll
  for (int m = 0; m < 8; ++m) {
    const int qg0 = iq * 256 + wr * 128 + m * 16 + ((lane >> 4) << 2);
#pragma unroll
    for (int r = 0; r < 4; ++r) {
      const int qg = qg0 + r;
      const float il = fin[bl * T_DIM + qg];
      float* orow = out + ((size_t)(batch0 + bl) * T_DIM + qg) * E_DIM;
#pragma unroll
      for (int n = 0; n < 4; ++n) {
        const int eg = ie * 256 + wc * 64 + n * 16 + (lane & 15);
        orow[eg] = acc[m][n][r] * il;
      }
    }
  }
}

extern "C" void kernel_launch(void* const* d_in, const int* in_sizes, int n_in,
                              void* d_out, int out_size, void* d_ws, size_t ws_size,
                              hipStream_t stream)
{
  const float* x    = (const float*)d_in[0];  // [8, 2048, 1024]
  const float* W    = (const float*)d_in[1];  // [3072, 1024]
  const float* bias = (const float*)d_in[2];  // [3072]
  float* out = (float*)d_out;

  char* ws = (char*)d_ws;
  const size_t ALIGN = 256;
  auto up = [&](size_t v) { return (v + ALIGN - 1) & ~(ALIGN - 1); };

  const size_t szWb = up((size_t)3 * E_DIM * E_DIM * 2);
  const size_t szX  = up((size_t)T_DIM * E_DIM * 2);       // bf16 [T,E] per batch
  const size_t szP  = up((size_t)T_DIM * T_DIM * 2);       // bf16 P' per batch
  const size_t szM  = up((size_t)T_DIM * 8 * 4);           // mc / lc per batch
  const size_t szI  = up((size_t)T_DIM * 4);               // fin per batch
  const size_t perB = 4 * szX + szP + 2 * szM + szI;

  int nb = 1;
  for (int cand = NBATCH; cand >= 1; --cand) {
    if (szWb + (size_t)cand * perB <= ws_size) { nb = cand; break; }
  }

  u16* Wb = (u16*)ws;
  {
    int n4 = 3 * E_DIM * E_DIM / 4;
    k_cvt<<<(n4 + 255) / 256, 256, 0, stream>>>(W, Wb, n4);
  }

  for (int b0 = 0; b0 < NBATCH; b0 += nb) {
    const int nbc = (NBATCH - b0 < nb) ? (NBATCH - b0) : nb;
    size_t o = szWb;
    u16* Xb    = (u16*)(ws + o);   o += (size_t)nbc * szX;
    u16* Qb    = (u16*)(ws + o);   o += (size_t)nbc * szX;
    u16* Kb    = (u16*)(ws + o);   o += (size_t)nbc * szX;
    u16* Vt    = (u16*)(ws + o);   o += (size_t)nbc * szX;
    u16* P     = (u16*)(ws + o);   o += (size_t)nbc * szP;
    float* mcA = (float*)(ws + o); o += (size_t)nbc * szM;
    float* lcA = (float*)(ws + o); o += (size_t)nbc * szM;
    float* fin = (float*)(ws + o); o += (size_t)nbc * szI;

    {
      int n4 = nbc * T_DIM * E_DIM / 4;
      k_cvt<<<(n4 + 255) / 256, 256, 0, stream>>>(x + (size_t)b0 * T_DIM * E_DIM, Xb, n4);
    }
    k_qkv<<<dim3(96 * nbc), 512, 0, stream>>>(Xb, Wb, bias, Qb, Kb, Vt);
    k_sp<<<dim3(36 * nbc), 512, 0, stream>>>(Qb, Kb, P, mcA, lcA);
    k_finish<<<dim3(nbc * T_DIM / 256), 256, 0, stream>>>(mcA, lcA, fin);
    k_pv<<<dim3(32 * nbc), 512, 0, stream>>>(P, Vt, mcA, fin, out, b0);
  }
}